// Round 2
// baseline (848.421 us; speedup 1.0000x reference)
//
#include <hip/hip_runtime.h>
#include <cstdint>

// Problem: M=16384, K=2048, N=2048 fp8(e4m3) delayed-scaling dense fwd.
#define M_DIM 16384
#define K_DIM 2048
#define N_DIM 2048

typedef float f32x4 __attribute__((ext_vector_type(4)));
typedef int   i32x8 __attribute__((ext_vector_type(8)));

// ---------------------------------------------------------------------------
// Kernel 1: quantize x [M,K] f32 -> fp8 e4m3, fused amax.
// 16 floats/thread: 4x float4 loads (64B/lane, full-line across the 4 instrs)
// -> one uint4 store (16B/lane). 8192 blocks x 256 thr x 16 = 33.5M elems.
// ---------------------------------------------------------------------------
__global__ __launch_bounds__(256) void quant_x_kernel(
    const float4* __restrict__ x, uint4* __restrict__ xq,
    const float* __restrict__ scale, unsigned int* __restrict__ amax)
{
    const int gid = blockIdx.x * 256 + threadIdx.x;   // 0 .. 2097151
    const float s = scale[0];
    float4 vv[4];
#pragma unroll
    for (int j = 0; j < 4; ++j) vv[j] = x[gid * 4 + j];

    float m = 0.0f;
    unsigned int pks[4];
#pragma unroll
    for (int j = 0; j < 4; ++j) {
        float4 v = vv[j];
        m = fmaxf(m, fmaxf(fmaxf(fabsf(v.x), fabsf(v.y)),
                           fmaxf(fabsf(v.z), fabsf(v.w))));
        unsigned int p0 = __builtin_amdgcn_cvt_pk_fp8_f32(v.x * s, v.y * s, 0, false);
        pks[j] = __builtin_amdgcn_cvt_pk_fp8_f32(v.z * s, v.w * s, p0, true);
    }
    xq[gid] = make_uint4(pks[0], pks[1], pks[2], pks[3]);

#pragma unroll
    for (int off = 32; off > 0; off >>= 1)
        m = fmaxf(m, __shfl_down(m, off, 64));
    __shared__ float red[4];
    if ((threadIdx.x & 63) == 0) red[threadIdx.x >> 6] = m;
    __syncthreads();
    if (threadIdx.x == 0) {
        m = fmaxf(fmaxf(red[0], red[1]), fmaxf(red[2], red[3]));
        atomicMax(amax, __float_as_uint(m));  // values >= 0: uint order == float order
    }
}

// ---------------------------------------------------------------------------
// Kernel 2: quantize + transpose kernel [K,N] f32 -> wq [N,K] fp8, fused amax.
// ---------------------------------------------------------------------------
__global__ __launch_bounds__(256) void quant_w_kernel(
    const float* __restrict__ w, uint8_t* __restrict__ wq,
    const float* __restrict__ scale, unsigned int* __restrict__ amax)
{
    __shared__ float tile[64][68];
    const int t = threadIdx.x;
    const int nb = blockIdx.x * 64;
    const int kb = blockIdx.y * 64;
    const float s = scale[1];
    float m = 0.0f;
#pragma unroll
    for (int j = 0; j < 4; ++j) {
        int f = j * 256 + t;
        int row = f >> 4;
        int c4 = f & 15;
        float4 v = *(const float4*)(w + (size_t)(kb + row) * N_DIM + nb + c4 * 4);
        m = fmaxf(m, fmaxf(fmaxf(fabsf(v.x), fabsf(v.y)),
                           fmaxf(fabsf(v.z), fabsf(v.w))));
        *(float4*)(&tile[row][c4 * 4]) = v;
    }
    __syncthreads();
    const int n = t >> 2, c = t & 3;
    unsigned int pk[4];
#pragma unroll
    for (int jj = 0; jj < 4; ++jj) {
        float f0 = tile[c * 16 + jj * 4 + 0][n] * s;
        float f1 = tile[c * 16 + jj * 4 + 1][n] * s;
        float f2 = tile[c * 16 + jj * 4 + 2][n] * s;
        float f3 = tile[c * 16 + jj * 4 + 3][n] * s;
        unsigned int p = __builtin_amdgcn_cvt_pk_fp8_f32(f0, f1, 0, false);
        pk[jj] = __builtin_amdgcn_cvt_pk_fp8_f32(f2, f3, p, true);
    }
    *(uint4*)(wq + (size_t)(nb + n) * K_DIM + kb + c * 16) = make_uint4(pk[0], pk[1], pk[2], pk[3]);

#pragma unroll
    for (int off = 32; off > 0; off >>= 1)
        m = fmaxf(m, __shfl_down(m, off, 64));
    __shared__ float red[4];
    if ((t & 63) == 0) red[t >> 6] = m;
    __syncthreads();
    if (t == 0) {
        m = fmaxf(fmaxf(red[0], red[1]), fmaxf(red[2], red[3]));
        atomicMax(amax, __float_as_uint(m));
    }
}

// ---------------------------------------------------------------------------
// Kernel 3: MX-scaled fp8 GEMM, deep-prefetch counted-vmcnt schedule.
//   C[m,n] = sum_k Aq[m,k]*Bq[n,k] via mfma_scale_f32_16x16x128_f8f6f4.
//
// Geometry: 256x256 tile, 512 thr = 8 waves (2M x 4N), 128x64/wave, BK=128B.
// LDS: 2 x (32KB A + 32KB B) = 128 KiB dynamic, 1 block/CU.
//
// Round-1 post-mortem: 8-barrier/K-step + 2-phase prefetch distance (~500cy)
// < HBM latency (~900cy) stalled all 8 lockstep waves at every vmcnt with no
// other block resident. Fix:
//  * ALL 8 staging rounds issued at phase 0 of each K-step (into the other
//    buffer) -> waits vmcnt(10)/(8)/(4) give every load 3-6 phases (~1000+cy)
//    to land. Never drain to 0 in the loop (exact vmcnt(2)/(0) on last iter,
//    no wrap-stage -> saves 32MB phantom fetch).
//  * Barriers 8 -> 3 per K-step: staging targets the OTHER buffer, so only
//    the three consumption points need vmcnt+barrier. Phases 2+3 merge into
//    one 16-MFMA region. Every barrier is preceded by an asm memory clobber,
//    which also fences compiler motion of LDS reads across buffer reuse.
//  * XCD-bijective block swizzle (512 blocks, id%8 = XCD round-robin): each
//    XCD gets an 8-bm-slab x all-bn -> A panels L2-resident (round-0 FETCH
//    showed 4x A refetch reaching HBM).
// Fragment read pattern kept from round 1 (peak 6 live frags, arch VGPR ~120
// + 128 acc = 248 <= 256): a read-once variant peaks at 8 frags -> 264 regs
// -> scratch spills, which would corrupt the vmcnt ledger.
//
// Ledger (per wave, FIFO, 2 loads/round, issue order Ah1,Ah1,Bn0,Bn0,Bn1,
// Bn1,Ah2,Ah2 at ph0 for buffer nxt):
//   end-ph0: vmcnt(10) retires Bn1(cur)  [issued prev iter ph0: ~3 phases]
//   end-ph1: vmcnt(8)  retires Ah2(cur)  [~4 phases]
//   end-ph3: vmcnt(4)  retires Ah1,Bn0(nxt) [~2.5 phases]
// ---------------------------------------------------------------------------
#define LDSBUF 32768

__global__ __launch_bounds__(512, 2) void gemm_fp8_kernel(
    const uint8_t* __restrict__ Aq, const uint8_t* __restrict__ Bq,
    const float* __restrict__ scale, float* __restrict__ C)
{
    extern __shared__ uint8_t lds[];
    uint8_t* const lA = lds;                  // [2][LDSBUF]
    uint8_t* const lB = lds + 2 * LDSBUF;     // [2][LDSBUF]

    const int tid  = threadIdx.x;
    const int wave = tid >> 6;
    const int lane = tid & 63;
    const int wm = wave >> 2, wn = wave & 3;  // 2(M) x 4(N) wave grid
    const int q = lane >> 4, r = lane & 15;

    // XCD-bijective swizzle: id%8 = XCD (round-robin dispatch). XCD k owns
    // bm in [8k,8k+8) x all bn -> A slab (4MB) reused within its private L2.
    const int id  = blockIdx.x;               // 0..511
    const int xcd = id & 7, idx = id >> 3;    // 64 blocks per XCD
    const int bm  = (xcd << 3) | (idx & 7);   // 0..63
    const int bn  = idx >> 3;                 // 0..7

    // Read scales up front, then drain all counters so the K-loop's counted
    // vmcnt tracks ONLY the global_load_lds stream.
    const float s0 = scale[0];
    const float s1 = scale[1];
    asm volatile("s_waitcnt vmcnt(0) lgkmcnt(0)" ::: "memory");

    // ---- staging lane constants ----
    const int seg = wave & 1;                 // segment (half-group) per wave
    const int wp  = wave >> 1;                // 0..3
    const int gbB = wp + ((wp >> 1) << 1);    // {0,1,4,5}
    const int npr = seg * 64 + lane;          // staging granule within group
    const int nin = npr ^ ((npr >> 3) & 1);   // involution -> logical granule
    const int srow = (nin >> 1) & 15;                         // row in group
    const int skb  = (((nin >> 1) >> 4) << 5) + ((nin & 1) << 4); // k-byte
    const int sdst = seg * 1024 + lane * 16;  // lane-linear LDS dst in group

    const uint8_t* aS = Aq + (size_t)(bm * 256 + srow) * K_DIM + skb;
    const uint8_t* bS = Bq + (size_t)(bn * 256 + srow) * K_DIM + skb;

#define STAGE_A(buf, kb, g)                                                          \
    __builtin_amdgcn_global_load_lds(                                                \
        (const __attribute__((address_space(1))) uint32_t*)(aS + (size_t)(g) * (16 * K_DIM) + (kb)), \
        (__attribute__((address_space(3))) uint32_t*)(lA + (buf) * LDSBUF + (g) * 2048 + sdst), 16, 0, 0)
#define STAGE_B(buf, kb, g)                                                          \
    __builtin_amdgcn_global_load_lds(                                                \
        (const __attribute__((address_space(1))) uint32_t*)(bS + (size_t)(g) * (16 * K_DIM) + (kb)), \
        (__attribute__((address_space(3))) uint32_t*)(lB + (buf) * LDSBUF + (g) * 2048 + sdst), 16, 0, 0)

    // ---- fragment read offsets (swizzled, matches staging involution) ----
    const int sb   = (lane >> 2) & 1;
    const int offL = (((lane << 1) ^ sb) << 4);
    const int offH = ((((lane << 1) + 1) ^ sb) << 4);

#define LDA(mi, g) { const uint8_t* pa = curA + (g) * 2048;                 \
        int4 lo = *(const int4*)(pa + offL);                                \
        int4 hi = *(const int4*)(pa + offH);                                \
        a_frag[mi] = (i32x8){lo.x,lo.y,lo.z,lo.w,hi.x,hi.y,hi.z,hi.w}; }
#define LDB(j, g) { const uint8_t* pb = curB + (g) * 2048;                  \
        int4 lo = *(const int4*)(pb + offL);                                \
        int4 hi = *(const int4*)(pb + offH);                                \
        b_frag[j] = (i32x8){lo.x,lo.y,lo.z,lo.w,hi.x,hi.y,hi.z,hi.w}; }

    f32x4 acc[8][4];
#pragma unroll
    for (int i = 0; i < 8; ++i)
#pragma unroll
        for (int j = 0; j < 4; ++j) acc[i][j] = (f32x4){0.f, 0.f, 0.f, 0.f};

    // ---- prologue: stage all 8 rounds of K-step 0 into buffer 0 ----
    STAGE_A(0, 0, wp);       STAGE_A(0, 0, 8 + wp);
    STAGE_B(0, 0, gbB);      STAGE_B(0, 0, 8 + gbB);
    STAGE_B(0, 0, 2 + gbB);  STAGE_B(0, 0, 10 + gbB);
    STAGE_A(0, 0, 4 + wp);   STAGE_A(0, 0, 12 + wp);
    asm volatile("s_waitcnt vmcnt(4)" ::: "memory");   // Ah1,Bn0 landed
    __builtin_amdgcn_s_barrier();

    const int SONE = 0x7F7F7F7F;   // e8m0 scale = 1.0 in every byte

#pragma unroll 2
    for (int t = 0; t < 16; ++t) {
        const int cur = t & 1, nxt = cur ^ 1;
        const int kbn = (t + 1) * 128;        // only used when t < 15
        uint8_t* const curA = lA + cur * LDSBUF;
        uint8_t* const curB = lB + cur * LDSBUF;
        i32x8 a_frag[4], b_frag[2];

        // ---- phase 0: A-low x B-low; issue ALL staging for next K-step ----
        LDA(0, wm * 8 + 0)  LDA(1, wm * 8 + 1)
        LDA(2, wm * 8 + 2)  LDA(3, wm * 8 + 3)
        LDB(0, wn * 4 + 0)  LDB(1, wn * 4 + 1)
        if (t < 15) {
            STAGE_A(nxt, kbn, wp);       STAGE_A(nxt, kbn, 8 + wp);
            STAGE_B(nxt, kbn, gbB);      STAGE_B(nxt, kbn, 8 + gbB);
            STAGE_B(nxt, kbn, 2 + gbB);  STAGE_B(nxt, kbn, 10 + gbB);
            STAGE_A(nxt, kbn, 4 + wp);   STAGE_A(nxt, kbn, 12 + wp);
        }
        __builtin_amdgcn_s_setprio(1);
#pragma unroll
        for (int mi = 0; mi < 4; ++mi)
#pragma unroll
            for (int j = 0; j < 2; ++j)
                acc[mi][j] = __builtin_amdgcn_mfma_scale_f32_16x16x128_f8f6f4(
                    a_frag[mi], b_frag[j], acc[mi][j], 0, 0, 0, SONE, 0, SONE);
        __builtin_amdgcn_s_setprio(0);
        if (t < 15) asm volatile("s_waitcnt vmcnt(10)" ::: "memory"); // Bn1 ready
        else        asm volatile("s_waitcnt vmcnt(2)"  ::: "memory");
        __builtin_amdgcn_s_barrier();

        // ---- phase 1: A-low x B-high ----
        LDB(0, wn * 4 + 2)  LDB(1, wn * 4 + 3)
        __builtin_amdgcn_s_setprio(1);
#pragma unroll
        for (int mi = 0; mi < 4; ++mi)
#pragma unroll
            for (int j = 0; j < 2; ++j)
                acc[mi][2 + j] = __builtin_amdgcn_mfma_scale_f32_16x16x128_f8f6f4(
                    a_frag[mi], b_frag[j], acc[mi][2 + j], 0, 0, 0, SONE, 0, SONE);
        __builtin_amdgcn_s_setprio(0);
        if (t < 15) asm volatile("s_waitcnt vmcnt(8)" ::: "memory");  // Ah2 ready
        else        asm volatile("s_waitcnt vmcnt(0)" ::: "memory");
        __builtin_amdgcn_s_barrier();

        // ---- phases 2+3 (merged, no mid-barrier): A-high x B-all ----
        LDA(0, wm * 8 + 4)  LDA(1, wm * 8 + 5)
        LDA(2, wm * 8 + 6)  LDA(3, wm * 8 + 7)
        LDB(0, wn * 4 + 0)  LDB(1, wn * 4 + 1)
        __builtin_amdgcn_s_setprio(1);
#pragma unroll
        for (int mi = 0; mi < 4; ++mi)
#pragma unroll
            for (int j = 0; j < 2; ++j)
                acc[4 + mi][j] = __builtin_amdgcn_mfma_scale_f32_16x16x128_f8f6f4(
                    a_frag[mi], b_frag[j], acc[4 + mi][j], 0, 0, 0, SONE, 0, SONE);
        __builtin_amdgcn_s_setprio(0);
        LDB(0, wn * 4 + 2)  LDB(1, wn * 4 + 3)
        __builtin_amdgcn_s_setprio(1);
#pragma unroll
        for (int mi = 0; mi < 4; ++mi)
#pragma unroll
            for (int j = 0; j < 2; ++j)
                acc[4 + mi][2 + j] = __builtin_amdgcn_mfma_scale_f32_16x16x128_f8f6f4(
                    a_frag[mi], b_frag[j], acc[4 + mi][2 + j], 0, 0, 0, SONE, 0, SONE);
        __builtin_amdgcn_s_setprio(0);
        if (t < 15) asm volatile("s_waitcnt vmcnt(4)" ::: "memory");  // next Ah1,Bn0
        __builtin_amdgcn_s_barrier();
    }
#undef STAGE_A
#undef STAGE_B
#undef LDA
#undef LDB

    // epilogue: D col = lane&15, row = q*4 + reg (m89-verified, shape-determined)
    const float sinv = (1.0f / s0) * (1.0f / s1);
#pragma unroll
    for (int mi = 0; mi < 8; ++mi) {
#pragma unroll
        for (int ni = 0; ni < 4; ++ni) {
            const int col  = bn * 256 + wn * 64 + ni * 16 + r;
            const int row0 = bm * 256 + wm * 128 + mi * 16 + q * 4;
#pragma unroll
            for (int rr = 0; rr < 4; ++rr)
                C[(size_t)(row0 + rr) * N_DIM + col] = acc[mi][ni][rr] * sinv;
        }
    }
}

// ---------------------------------------------------------------------------
// Kernel 4: scale update (faithful _sf_compute incl. tf.where ordering) +
// rolled amax history (always zeros for 1-row history).
// ---------------------------------------------------------------------------
__global__ void finalize_kernel(const float* __restrict__ scale,
                                const unsigned int* __restrict__ amax_bits,
                                float* __restrict__ out_tail)
{
    const int i = threadIdx.x;
    if (i < 2) {
        const float amax = __uint_as_float(amax_bits[i]);
        const float sc = scale[i];
        const float e = floorf(log2f(448.0f / amax));
        float sf = roundf(exp2f(fabsf(e)));
        sf = (amax > 0.0f) ? sf : sc;
        sf = isinf(amax) ? sf : sc;      // faithful: finite amax collapses to scale
        if (e < 0.0f) sf = 1.0f / sf;
        out_tail[i] = sf;                // new_scale
        out_tail[2 + i] = 0.0f;          // rolled history (single row -> zeros)
    }
}

// ---------------------------------------------------------------------------
extern "C" void kernel_launch(void* const* d_in, const int* in_sizes, int n_in,
                              void* d_out, int out_size, void* d_ws, size_t ws_size,
                              hipStream_t stream)
{
    const float* x     = (const float*)d_in[0];
    const float* w     = (const float*)d_in[1];
    const float* scale = (const float*)d_in[2];

    uint8_t* ws = (uint8_t*)d_ws;
    uint8_t* xq = ws;                                            // M*K fp8 (32 MB)
    uint8_t* wq = ws + (size_t)M_DIM * K_DIM;                    // N*K fp8 (4 MB)
    unsigned int* amax = (unsigned int*)(ws + (size_t)M_DIM * K_DIM + (size_t)N_DIM * K_DIM);

    static int lds_opt_in = 0;           // one-time 128 KiB dynamic-LDS opt-in
    if (!lds_opt_in) {
        hipFuncSetAttribute((const void*)gemm_fp8_kernel,
                            hipFuncAttributeMaxDynamicSharedMemorySize, 131072);
        lds_opt_in = 1;
    }

    hipMemsetAsync(amax, 0, 2 * sizeof(unsigned int), stream);

    quant_x_kernel<<<8192, 256, 0, stream>>>(
        (const float4*)x, (uint4*)xq, scale, amax);

    dim3 gw(N_DIM / 64, K_DIM / 64);
    quant_w_kernel<<<gw, 256, 0, stream>>>(w, wq, scale, amax + 1);

    gemm_fp8_kernel<<<512, 512, 131072, stream>>>(xq, wq, scale, (float*)d_out);

    finalize_kernel<<<1, 64, 0, stream>>>(scale, amax,
                                          (float*)d_out + (size_t)M_DIM * N_DIM);
}

// Round 3
// 328.150 us; speedup vs baseline: 2.5855x; 2.5855x over previous
//
#include <hip/hip_runtime.h>
#include <cstdint>

// Problem: M=16384, K=2048, N=2048 fp8(e4m3) delayed-scaling dense fwd.
#define M_DIM 16384
#define K_DIM 2048
#define N_DIM 2048

typedef float f32x4 __attribute__((ext_vector_type(4)));
typedef int   i32x8 __attribute__((ext_vector_type(8)));

// ---------------------------------------------------------------------------
// Kernel 1 (FUSED): quantize x [M,K] -> fp8 (blocks 0..4095) and
// quantize+transpose w [K,N] -> wq [N,K] fp8 (blocks 4096..5119).
// Bodies are byte-identical to the round-0 verified kernels; fusion only
// removes one kernel-launch boundary (non-GEMM time ~240us >> sum of
// kernel rooflines ~30us => per-op overhead suspected dominant).
// ---------------------------------------------------------------------------
__global__ __launch_bounds__(256) void quant_fused_kernel(
    const float4* __restrict__ x, uint4* __restrict__ xq,
    const float* __restrict__ w, uint8_t* __restrict__ wq,
    const float* __restrict__ scale, unsigned int* __restrict__ amax)
{
    __shared__ float tile[64][68];
    __shared__ float red[4];
    const int bid = blockIdx.x;
    const int t = threadIdx.x;
    float m = 0.0f;

    if (bid < 4096) {
        // ---- x path: grid-stride float4, fused amax ----
        const int gid = bid * 256 + t;                // 0 .. 1048575
        const float s = scale[0];
#pragma unroll
        for (int j = 0; j < 8; ++j) {
            float4 v = x[gid + j * 1048576];
            m = fmaxf(m, fmaxf(fmaxf(fabsf(v.x), fabsf(v.y)),
                               fmaxf(fabsf(v.z), fabsf(v.w))));
            unsigned int p0 = __builtin_amdgcn_cvt_pk_fp8_f32(v.x * s, v.y * s, 0, false);
            unsigned int p  = __builtin_amdgcn_cvt_pk_fp8_f32(v.z * s, v.w * s, p0, true);
            ((unsigned int*)xq)[gid + j * 1048576] = p;   // 4 fp8/dword, coalesced
        }
    } else {
        // ---- w path: 64x64 LDS transpose tile, fused amax ----
        const int b2 = bid - 4096;                    // 0..1023
        const int nb = (b2 & 31) << 6;
        const int kb = (b2 >> 5) << 6;
        const float s = scale[1];
#pragma unroll
        for (int j = 0; j < 4; ++j) {
            int f = j * 256 + t;
            int row = f >> 4;
            int c4 = f & 15;
            float4 v = *(const float4*)(w + (size_t)(kb + row) * N_DIM + nb + c4 * 4);
            m = fmaxf(m, fmaxf(fmaxf(fabsf(v.x), fabsf(v.y)),
                               fmaxf(fabsf(v.z), fabsf(v.w))));
            *(float4*)(&tile[row][c4 * 4]) = v;
        }
        __syncthreads();
        const int n = t >> 2, c = t & 3;
        unsigned int pk[4];
#pragma unroll
        for (int jj = 0; jj < 4; ++jj) {
            float f0 = tile[c * 16 + jj * 4 + 0][n] * s;
            float f1 = tile[c * 16 + jj * 4 + 1][n] * s;
            float f2 = tile[c * 16 + jj * 4 + 2][n] * s;
            float f3 = tile[c * 16 + jj * 4 + 3][n] * s;
            unsigned int p = __builtin_amdgcn_cvt_pk_fp8_f32(f0, f1, 0, false);
            pk[jj] = __builtin_amdgcn_cvt_pk_fp8_f32(f2, f3, p, true);
        }
        *(uint4*)(wq + (size_t)(nb + n) * K_DIM + kb + c * 16) =
            make_uint4(pk[0], pk[1], pk[2], pk[3]);
    }

    // ---- common block reduction + device atomic (amax[0]=x, amax[1]=w) ----
#pragma unroll
    for (int off = 32; off > 0; off >>= 1)
        m = fmaxf(m, __shfl_down(m, off, 64));
    if ((t & 63) == 0) red[t >> 6] = m;
    __syncthreads();
    if (t == 0) {
        m = fmaxf(fmaxf(red[0], red[1]), fmaxf(red[2], red[3]));
        atomicMax(amax + (bid < 4096 ? 0 : 1), __float_as_uint(m));
    }
}

// ---------------------------------------------------------------------------
// Kernel 2: MX-scaled fp8 GEMM.  C[m,n] = sum_k Aq[m,k]*Bq[n,k].
// VERBATIM round-0 verified kernel (97us, VGPR 80, 33KB LDS, multi-block
// TLP absorbs the barrier drains — the two 256^2 restructures regressed on
// pipeline depth [r1] then scratch spills [r2: WRITE_SIZE 1.49GB]).
// Added: finalize tail folded into block (0,0) lanes 0-1 (amax atomics
// complete before this kernel launches; stream order gives visibility).
//
// LDS layout (per matrix): 8 row-groups of 16 rows. Group g occupies
// [g*2080, g*2080+1024) = fragment half0 and [g*2080+1040, g*2080+2064) =
// half1, 16B pad between halves. Lane l's fragment: lo b128 at
// g*2080 + l*32 + (l>>5)*16, hi at +16. 8-phase bank structure,
// conflict count 4/read is the wave64-b128 structural minimum.
// ---------------------------------------------------------------------------
#define GSTRIDE 2080
__global__ __launch_bounds__(256) void gemm_fp8_kernel(
    const uint8_t* __restrict__ Aq, const uint8_t* __restrict__ Bq,
    const float* __restrict__ scale, const unsigned int* __restrict__ amax_bits,
    float* __restrict__ C)
{
    __shared__ uint8_t lA[8 * GSTRIDE];
    __shared__ uint8_t lB[8 * GSTRIDE];
    const int tid  = threadIdx.x;
    const int wave = tid >> 6;
    const int lane = tid & 63;
    const int wm = wave >> 1, wn = wave & 1;   // 2x2 wave grid, 64x64 per wave
    const int q = lane >> 4, r = lane & 15;

    const int bn = blockIdx.x;                 // 0..15
    const int bm = blockIdx.y;                 // 0..127
    const size_t a_base = (size_t)bm * 128 * K_DIM;
    const size_t b_base = (size_t)bn * 128 * K_DIM;

    // Staging geometry: wave handles segments s = j*4 + wave, s = 2g + h.
    int srow[4], skoff[4], sdst[4];
#pragma unroll
    for (int j = 0; j < 4; ++j) {
        const int s  = j * 4 + wave;
        const int g  = s >> 1, hh = s & 1;
        const int fl = hh * 32 + (lane >> 1);
        srow[j]  = g * 16 + (fl & 15);
        skoff[j] = (fl >> 4) * 32 + (lane & 1) * 16;
        sdst[j]  = g * GSTRIDE + hh * 1040 + lane * 16;
    }
    // Fragment read base offset for this lane (within a group)
    const int frag_off = lane * 32 + (lane >> 5) * 16;

    f32x4 acc[4][4];
#pragma unroll
    for (int i = 0; i < 4; ++i)
#pragma unroll
        for (int j = 0; j < 4; ++j) acc[i][j] = (f32x4){0.f, 0.f, 0.f, 0.f};

    const int SONE = 0x7F7F7F7F;   // e8m0 scale = 1.0 in every byte

    for (int kt = 0; kt < K_DIM / 128; ++kt) {
        __syncthreads();
        const size_t kg = (size_t)kt * 128;
#pragma unroll
        for (int j = 0; j < 4; ++j) {
            const uint8_t* ga = Aq + a_base + (size_t)srow[j] * K_DIM + kg + skoff[j];
            const uint8_t* gb = Bq + b_base + (size_t)srow[j] * K_DIM + kg + skoff[j];
            __builtin_amdgcn_global_load_lds(
                (const __attribute__((address_space(1))) uint32_t*)ga,
                (__attribute__((address_space(3))) uint32_t*)(lA + sdst[j]), 16, 0, 0);
            __builtin_amdgcn_global_load_lds(
                (const __attribute__((address_space(1))) uint32_t*)gb,
                (__attribute__((address_space(3))) uint32_t*)(lB + sdst[j]), 16, 0, 0);
        }
        __syncthreads();

        i32x8 a_frag[4], b_frag[4];
#pragma unroll
        for (int mi = 0; mi < 4; ++mi) {
            const uint8_t* pa = lA + (wm * 4 + mi) * GSTRIDE + frag_off;
            int4 lo = *(const int4*)pa;
            int4 hi = *(const int4*)(pa + 16);
            a_frag[mi] = (i32x8){lo.x, lo.y, lo.z, lo.w, hi.x, hi.y, hi.z, hi.w};
        }
#pragma unroll
        for (int ni = 0; ni < 4; ++ni) {
            const uint8_t* pb = lB + (wn * 4 + ni) * GSTRIDE + frag_off;
            int4 lo = *(const int4*)pb;
            int4 hi = *(const int4*)(pb + 16);
            b_frag[ni] = (i32x8){lo.x, lo.y, lo.z, lo.w, hi.x, hi.y, hi.z, hi.w};
        }
#pragma unroll
        for (int mi = 0; mi < 4; ++mi)
#pragma unroll
            for (int ni = 0; ni < 4; ++ni)
                acc[mi][ni] = __builtin_amdgcn_mfma_scale_f32_16x16x128_f8f6f4(
                    a_frag[mi], b_frag[ni], acc[mi][ni],
                    0 /*cbsz: fp8*/, 0 /*blgp: fp8*/,
                    0, SONE, 0, SONE);
    }

    // epilogue: D col = lane&15, row = q*4 + reg (m89-verified, shape-determined)
    const float sinv = (1.0f / scale[0]) * (1.0f / scale[1]);
#pragma unroll
    for (int mi = 0; mi < 4; ++mi) {
#pragma unroll
        for (int ni = 0; ni < 4; ++ni) {
            const int col  = bn * 128 + wn * 64 + ni * 16 + r;
            const int row0 = bm * 128 + wm * 64 + mi * 16 + q * 4;
#pragma unroll
            for (int rr = 0; rr < 4; ++rr)
                C[(size_t)(row0 + rr) * N_DIM + col] = acc[mi][ni][rr] * sinv;
        }
    }

    // ---- finalize tail (was kernel 4): block (0,0), lanes 0-1 ----
    // Faithful _sf_compute incl. tf.where ordering; rolled 1-row history = 0.
    if (blockIdx.x == 0 && blockIdx.y == 0 && tid < 2) {
        float* out_tail = C + (size_t)M_DIM * N_DIM;
        const float amax = __uint_as_float(amax_bits[tid]);
        const float sc = scale[tid];
        const float e = floorf(log2f(448.0f / amax));
        float sf = roundf(exp2f(fabsf(e)));
        sf = (amax > 0.0f) ? sf : sc;
        sf = isinf(amax) ? sf : sc;      // faithful: finite amax collapses to scale
        if (e < 0.0f) sf = 1.0f / sf;
        out_tail[tid] = sf;              // new_scale
        out_tail[2 + tid] = 0.0f;        // rolled history (single row -> zeros)
    }
}

// ---------------------------------------------------------------------------
extern "C" void kernel_launch(void* const* d_in, const int* in_sizes, int n_in,
                              void* d_out, int out_size, void* d_ws, size_t ws_size,
                              hipStream_t stream)
{
    const float* x     = (const float*)d_in[0];
    const float* w     = (const float*)d_in[1];
    const float* scale = (const float*)d_in[2];

    uint8_t* ws = (uint8_t*)d_ws;
    uint8_t* xq = ws;                                            // M*K fp8 (32 MB)
    uint8_t* wq = ws + (size_t)M_DIM * K_DIM;                    // N*K fp8 (4 MB)
    unsigned int* amax = (unsigned int*)(ws + (size_t)M_DIM * K_DIM + (size_t)N_DIM * K_DIM);

    hipMemsetAsync(amax, 0, 2 * sizeof(unsigned int), stream);

    quant_fused_kernel<<<5120, 256, 0, stream>>>(
        (const float4*)x, (uint4*)xq, w, wq, scale, amax);

    dim3 gg(N_DIM / 128, M_DIM / 128);
    gemm_fp8_kernel<<<gg, 256, 0, stream>>>(xq, wq, scale, amax, (float*)d_out);
}